// Round 5
// baseline (202.785 us; speedup 1.0000x reference)
//
#include <hip/hip_runtime.h>

#define N_NODES 50000
#define N_EDGES 800000
#define CH 128
#define WT_PAD 136      // LDS row stride in shorts (272 B: 16B-aligned, 2-way-free banks)
#define DUMMY N_NODES   // g row 50000 is zeroed; CSR padding points here
#define SLOT_LOG 6      // 64 slots per node (max degree ~45 for Poisson(16))
#define AGG_BLKS 1563   // ceil(50000/32) blocks (both channel halves in one pass)

#define NBUCK 391       // ceil(50000/128) buckets of 128 nodes
#define BUCK_CAP 3072   // mean 2046, sigma ~45 -> +22 sigma headroom
#define EPB 4096        // edges per partition block
#define PART_BLOCKS 196 // ceil(800000/4096)

typedef __attribute__((ext_vector_type(8))) short short8;   // 8 bf16 = one MFMA A/B frag
typedef __attribute__((ext_vector_type(4))) float floatx4;  // MFMA C/D frag / NT stores

__device__ __forceinline__ short f2bf(float f) {  // RNE float->bf16
    union { float f; unsigned u; } v; v.f = f;
    unsigned r = v.u + 0x7fff + ((v.u >> 16) & 1);
    return (short)(r >> 16);
}
__device__ __forceinline__ float bflo(unsigned u) {
    union { unsigned u; float f; } v; v.u = u << 16; return v.f;
}
__device__ __forceinline__ float bfhi(unsigned u) {
    union { unsigned u; float f; } v; v.u = u & 0xffff0000u; return v.f;
}

// ---------------- prep: weights transpose/fuse + zero bucket counters -----------------

__global__ __launch_bounds__(256) void prep_kernel(const float* __restrict__ W1,
                                                   const float* __restrict__ W2,
                                                   const float* __restrict__ W3,
                                                   const float* __restrict__ b2,
                                                   const float* __restrict__ b3,
                                                   unsigned short* __restrict__ Wt1,
                                                   unsigned short* __restrict__ Wt23,
                                                   float* __restrict__ b23,
                                                   int* __restrict__ bucket_cnt,
                                                   unsigned int* __restrict__ gdummy) {
    int i = blockIdx.x * blockDim.x + threadIdx.x;   // 66*256 = 16896 threads
    if (i < 128 * 128) {
        int n = i >> 7, k = i & 127;
        Wt1[i] = (unsigned short)f2bf(W1[k * 128 + n]);
        float w = (n < 64) ? W2[k * 64 + n] : W3[k * 64 + (n - 64)];
        Wt23[i] = (unsigned short)f2bf(w);
    } else if (i < 128 * 128 + 128) {
        int k2 = i - 128 * 128;
        b23[k2] = (k2 < 64) ? b2[k2] : b3[k2 - 64];
    } else if (i < 128 * 128 + 192) {
        gdummy[i - (128 * 128 + 128)] = 0;           // 64 uints = 128 bf16 zeros
    }
    if (i < NBUCK) bucket_cnt[i] = 0;
}

// ---------------- Phase A: radix-partition edges into 391 dst-buckets -----------------
// Per block: LDS histogram -> LDS scan -> one global atomic per (block,bucket) ->
// bucket-sorted LDS staging -> coalesced u32 flush.

__global__ __launch_bounds__(256) void partition(const int* __restrict__ ei,
                                                 int* __restrict__ bucket_cnt,
                                                 unsigned* __restrict__ bucket_data) {
    __shared__ int hcnt[512], hscan[512], htmp[512];   // hist + inclusive scan (ping-pong)
    __shared__ int s_shift[512];                        // base_g - base_l per bucket
    __shared__ unsigned stg[EPB];                       // bucket-sorted packed edges
    __shared__ int dsti[EPB];                           // global index per staged edge
    int tid = threadIdx.x;
    int e0 = blockIdx.x * EPB;

    for (int i = tid; i < 512; i += 256) hcnt[i] = 0;
    __syncthreads();
    for (int j = tid; j < EPB; j += 256) {
        int e = e0 + j;
        if (e < N_EDGES) atomicAdd(&hcnt[ei[N_EDGES + e] >> 7], 1);
    }
    __syncthreads();
    for (int i = tid; i < 512; i += 256) hscan[i] = hcnt[i];
    __syncthreads();
    for (int off = 1; off < 512; off <<= 1) {           // Hillis-Steele inclusive scan
        for (int i = tid; i < 512; i += 256) htmp[i] = hscan[i] + (i >= off ? hscan[i - off] : 0);
        __syncthreads();
        for (int i = tid; i < 512; i += 256) hscan[i] = htmp[i];
        __syncthreads();
    }
    // exclusive base_l = hscan - hcnt; allocate global space; cursor starts at base_l
    for (int b = tid; b < NBUCK; b += 256) {
        int c = hcnt[b];
        int excl = hscan[b] - c;
        int g = (c > 0) ? atomicAdd(&bucket_cnt[b], c) : 0;
        s_shift[b] = g - excl;
        htmp[b] = excl;                                 // htmp reused as cursor
    }
    __syncthreads();
    for (int j = tid; j < EPB; j += 256) {              // stage bucket-sorted
        int e = e0 + j;
        if (e < N_EDGES) {
            int src = ei[e];
            int d = ei[N_EDGES + e];
            int b = d >> 7;
            int pos = atomicAdd(&htmp[b], 1);           // LDS cursor
            stg[pos] = ((unsigned)(d & 127) << 16) | (unsigned)src;
            int gidx = s_shift[b] + pos;                // index within bucket region
            dsti[pos] = (gidx < BUCK_CAP) ? (b * BUCK_CAP + gidx) : -1;
        }
    }
    __syncthreads();
    int tot = N_EDGES - e0; if (tot > EPB) tot = EPB;
    for (int j = tid; j < tot; j += 256) {              // coalesced runs per bucket
        int di = dsti[j];
        if (di >= 0) bucket_data[di] = stg[j];
    }
}

// ---------------- Phase B: per-bucket CSR rows built entirely in LDS ------------------
// LDS atomics for ranks (no fabric), DUMMY pad in LDS, fully coalesced flush of
// counts + slot rows. One block per bucket (128 nodes x 64 slots = 16 KB).

__global__ __launch_bounds__(256) void csr_build(const unsigned* __restrict__ bucket_data,
                                                 const int* __restrict__ bucket_cnt,
                                                 int* __restrict__ counts,
                                                 unsigned short* __restrict__ sorted_src) {
    __shared__ uint4 slots4[1024];                      // 128 rows x 64 shorts = 16 KB
    __shared__ int ctr[128];
    unsigned short* slots = (unsigned short*)slots4;
    int tid = threadIdx.x, b = blockIdx.x;

    for (int i = tid; i < 128; i += 256) ctr[i] = 0;
    const unsigned dpat = ((unsigned)DUMMY) | (((unsigned)DUMMY) << 16);
    for (int i = tid; i < 1024; i += 256) slots4[i] = make_uint4(dpat, dpat, dpat, dpat);
    __syncthreads();

    int cnt = bucket_cnt[b]; if (cnt > BUCK_CAP) cnt = BUCK_CAP;
    const unsigned* bd = bucket_data + b * BUCK_CAP;
    for (int j = tid; j < cnt; j += 256) {
        unsigned w = bd[j];
        int dl = (int)(w >> 16);
        int r = atomicAdd(&ctr[dl], 1);                 // LDS atomic: fast
        if (r < 64) slots[(dl << 6) + r] = (unsigned short)(w & 0xffffu);
    }
    __syncthreads();

    int node0 = b << 7;
    for (int i = tid; i < 128; i += 256)
        if (node0 + i < N_NODES) counts[node0 + i] = ctr[i];
    uint4* gs = (uint4*)(sorted_src + ((size_t)node0 << SLOT_LOG));
    for (int k = tid; k < 1024; k += 256) {             // 8 uint4 per row, coalesced
        int row = k >> 3;
        if (node0 + row < N_NODES) gs[k] = slots4[k];
    }
}

// ---------------- MFMA GEMM: g[n][ch] = bf16( dinv[n] * sum_c A[n][c]*W[c][ch] ) -------
// dinv is computed on the fly as rsqrt(deg+1); deg-0 nodes get rsqrt(1)=1 automatically.

template <bool A_BF16>
__global__ __launch_bounds__(256) void gemm_mfma(const void* __restrict__ Ain,
                                                 const unsigned short* __restrict__ Wt,
                                                 const int* __restrict__ degs,
                                                 unsigned short* __restrict__ g) {
    __shared__ unsigned short lds[128 * WT_PAD];  // 34816 B; reused by epilogue
    int tid = threadIdx.x;
    int wave = tid >> 6, lane = tid & 63;
    int quad = lane >> 4, ln = lane & 15;

    {   // stage Wt (16384 shorts)
        int r = tid >> 1, h = tid & 1;
        const int4* src = (const int4*)(Wt + r * 128 + h * 64);
#pragma unroll
        for (int i = 0; i < 8; ++i)
            *(int4*)&lds[r * WT_PAD + h * 64 + i * 8] = src[i];
    }

    int row_base = blockIdx.x * 64 + wave * 16;
    int arow = row_base + ln;
    bool ok = arow < N_NODES;
    short8 afrag[4];
    if (A_BF16) {
        const unsigned short* A = (const unsigned short*)Ain;
#pragma unroll
        for (int kk = 0; kk < 4; ++kk) {
            short8 v = {};
            if (ok) v = *(const short8*)(A + arow * 128 + kk * 32 + quad * 8);
            afrag[kk] = v;
        }
    } else {
        const float* A = (const float*)Ain;
#pragma unroll
        for (int kk = 0; kk < 4; ++kk) {
            short8 v = {};
            if (ok) {
                const floatx4* p = (const floatx4*)(A + arow * 128 + kk * 32 + quad * 8);
                floatx4 fa = p[0], fb = p[1];
                v[0] = f2bf(fa.x); v[1] = f2bf(fa.y); v[2] = f2bf(fa.z); v[3] = f2bf(fa.w);
                v[4] = f2bf(fb.x); v[5] = f2bf(fb.y); v[6] = f2bf(fb.z); v[7] = f2bf(fb.w);
            }
            afrag[kk] = v;
        }
    }
    __syncthreads();

    floatx4 acc[8] = {};
#pragma unroll
    for (int n0 = 0; n0 < 8; ++n0) {
#pragma unroll
        for (int kk = 0; kk < 4; ++kk) {
            short8 b = *(const short8*)&lds[(n0 * 16 + ln) * WT_PAD + kk * 32 + quad * 8];
            acc[n0] = __builtin_amdgcn_mfma_f32_16x16x32_bf16(afrag[kk], b, acc[n0], 0, 0, 0);
        }
    }

    __syncthreads();  // done with Wt; reuse LDS for epilogue transpose
    unsigned short* st = &lds[wave * 16 * WT_PAD];
    float dv[4];
#pragma unroll
    for (int r = 0; r < 4; ++r) {
        int node = row_base + quad * 4 + r;
        dv[r] = (node < N_NODES) ? rsqrtf((float)(degs[node] + 1)) : 0.f;
    }
#pragma unroll
    for (int n0 = 0; n0 < 8; ++n0)
#pragma unroll
        for (int r = 0; r < 4; ++r)
            st[(quad * 4 + r) * WT_PAD + n0 * 16 + ln] =
                (unsigned short)f2bf(acc[n0][r] * dv[r]);
    __syncthreads();

#pragma unroll
    for (int i = 0; i < 4; ++i) {
        int row = i * 4 + quad;
        int node = row_base + row;
        short8 v = *(const short8*)&st[row * WT_PAD + ln * 8];
        if (node < N_NODES) *(short8*)(g + node * 128 + ln * 8) = v;
    }
}

// ---------------- aggregation: both channel halves in ONE pass (8 lanes/node) ----------
// srcs/degs metadata read once; 16 gathers in flight per 8-edge chunk.

#define UNPACK_ADD(t0,t1,t2,t3,t4,t5,t6,t7, v)                                  \
    t0 += bflo(v.x); t1 += bfhi(v.x); t2 += bflo(v.y); t3 += bfhi(v.y);         \
    t4 += bflo(v.z); t5 += bfhi(v.z); t6 += bflo(v.w); t7 += bfhi(v.w);

template <int MODE>  // 0: bf16 out [N][128]; 1: fp32 split out (x1 | x2)
__global__ __launch_bounds__(256) void aggregate_bf16(const unsigned short* __restrict__ g,
                                                      const int* __restrict__ degs,
                                                      const unsigned short* __restrict__ srcs,
                                                      const float* __restrict__ bias,
                                                      void* __restrict__ outp) {
    int n = blockIdx.x * 32 + (threadIdx.x >> 3);
    if (n >= N_NODES) return;
    int c4 = threadIdx.x & 7;                   // uint4 index within each half-row
    const uint4* grow = (const uint4*)g;        // 16 uint4 per full row
    uint4 uL = grow[n * 16 + c4];               // self-loop, half 0
    uint4 uH = grow[n * 16 + 8 + c4];           // self-loop, half 1
    float A0 = bflo(uL.x), A1 = bfhi(uL.x), A2 = bflo(uL.y), A3 = bfhi(uL.y);
    float A4 = bflo(uL.z), A5 = bfhi(uL.z), A6 = bflo(uL.w), A7 = bfhi(uL.w);
    float B0 = 0.f, B1 = 0.f, B2 = 0.f, B3 = 0.f, B4 = 0.f, B5 = 0.f, B6 = 0.f, B7 = 0.f;
    float C0 = bflo(uH.x), C1 = bfhi(uH.x), C2 = bflo(uH.y), C3 = bfhi(uH.y);
    float C4 = bflo(uH.z), C5 = bfhi(uH.z), C6 = bflo(uH.w), C7 = bfhi(uH.w);
    float D0 = 0.f, D1 = 0.f, D2 = 0.f, D3 = 0.f, D4 = 0.f, D5 = 0.f, D6 = 0.f, D7 = 0.f;
    int deg = degs[n];
    int degc = deg > 64 ? 64 : deg;
    int beg = n << SLOT_LOG;
    int pend = beg + ((degc + 3) & ~3);         // pad slots hold DUMMY (zero row)
    int e = beg;
    for (; e + 8 <= pend; e += 8) {
        ushort4 sa = *(const ushort4*)&srcs[e];
        ushort4 sb = *(const ushort4*)&srcs[e + 4];
        uint4 l0 = grow[sa.x * 16 + c4];      uint4 h0 = grow[sa.x * 16 + 8 + c4];
        uint4 l1 = grow[sa.y * 16 + c4];      uint4 h1 = grow[sa.y * 16 + 8 + c4];
        uint4 l2 = grow[sa.z * 16 + c4];      uint4 h2 = grow[sa.z * 16 + 8 + c4];
        uint4 l3 = grow[sa.w * 16 + c4];      uint4 h3 = grow[sa.w * 16 + 8 + c4];
        uint4 l4 = grow[sb.x * 16 + c4];      uint4 h4 = grow[sb.x * 16 + 8 + c4];
        uint4 l5 = grow[sb.y * 16 + c4];      uint4 h5 = grow[sb.y * 16 + 8 + c4];
        uint4 l6 = grow[sb.z * 16 + c4];      uint4 h6 = grow[sb.z * 16 + 8 + c4];
        uint4 l7 = grow[sb.w * 16 + c4];      uint4 h7 = grow[sb.w * 16 + 8 + c4];
        UNPACK_ADD(A0,A1,A2,A3,A4,A5,A6,A7, l0)
        UNPACK_ADD(B0,B1,B2,B3,B4,B5,B6,B7, l1)
        UNPACK_ADD(A0,A1,A2,A3,A4,A5,A6,A7, l2)
        UNPACK_ADD(B0,B1,B2,B3,B4,B5,B6,B7, l3)
        UNPACK_ADD(A0,A1,A2,A3,A4,A5,A6,A7, l4)
        UNPACK_ADD(B0,B1,B2,B3,B4,B5,B6,B7, l5)
        UNPACK_ADD(A0,A1,A2,A3,A4,A5,A6,A7, l6)
        UNPACK_ADD(B0,B1,B2,B3,B4,B5,B6,B7, l7)
        UNPACK_ADD(C0,C1,C2,C3,C4,C5,C6,C7, h0)
        UNPACK_ADD(D0,D1,D2,D3,D4,D5,D6,D7, h1)
        UNPACK_ADD(C0,C1,C2,C3,C4,C5,C6,C7, h2)
        UNPACK_ADD(D0,D1,D2,D3,D4,D5,D6,D7, h3)
        UNPACK_ADD(C0,C1,C2,C3,C4,C5,C6,C7, h4)
        UNPACK_ADD(D0,D1,D2,D3,D4,D5,D6,D7, h5)
        UNPACK_ADD(C0,C1,C2,C3,C4,C5,C6,C7, h6)
        UNPACK_ADD(D0,D1,D2,D3,D4,D5,D6,D7, h7)
    }
    if (e < pend) {  // exactly one 4-wide chunk (pend-beg is a multiple of 4)
        ushort4 sa = *(const ushort4*)&srcs[e];
        uint4 l0 = grow[sa.x * 16 + c4];      uint4 h0 = grow[sa.x * 16 + 8 + c4];
        uint4 l1 = grow[sa.y * 16 + c4];      uint4 h1 = grow[sa.y * 16 + 8 + c4];
        uint4 l2 = grow[sa.z * 16 + c4];      uint4 h2 = grow[sa.z * 16 + 8 + c4];
        uint4 l3 = grow[sa.w * 16 + c4];      uint4 h3 = grow[sa.w * 16 + 8 + c4];
        UNPACK_ADD(A0,A1,A2,A3,A4,A5,A6,A7, l0)
        UNPACK_ADD(B0,B1,B2,B3,B4,B5,B6,B7, l1)
        UNPACK_ADD(A0,A1,A2,A3,A4,A5,A6,A7, l2)
        UNPACK_ADD(B0,B1,B2,B3,B4,B5,B6,B7, l3)
        UNPACK_ADD(C0,C1,C2,C3,C4,C5,C6,C7, h0)
        UNPACK_ADD(D0,D1,D2,D3,D4,D5,D6,D7, h1)
        UNPACK_ADD(C0,C1,C2,C3,C4,C5,C6,C7, h2)
        UNPACK_ADD(D0,D1,D2,D3,D4,D5,D6,D7, h3)
    }
    A0 += B0; A1 += B1; A2 += B2; A3 += B3; A4 += B4; A5 += B5; A6 += B6; A7 += B7;
    C0 += D0; C1 += D1; C2 += D2; C3 += D3; C4 += D4; C5 += D5; C6 += D6; C7 += D7;
    float d = rsqrtf((float)(deg + 1));
    float4 bL0 = ((const float4*)bias)[c4 * 2];
    float4 bL1 = ((const float4*)bias)[c4 * 2 + 1];
    float4 bH0 = ((const float4*)bias)[16 + c4 * 2];
    float4 bH1 = ((const float4*)bias)[16 + c4 * 2 + 1];
    float p0 = fmaxf(d * A0 + bL0.x, 0.f), p1 = fmaxf(d * A1 + bL0.y, 0.f);
    float p2 = fmaxf(d * A2 + bL0.z, 0.f), p3 = fmaxf(d * A3 + bL0.w, 0.f);
    float p4 = fmaxf(d * A4 + bL1.x, 0.f), p5 = fmaxf(d * A5 + bL1.y, 0.f);
    float p6 = fmaxf(d * A6 + bL1.z, 0.f), p7 = fmaxf(d * A7 + bL1.w, 0.f);
    float q0 = fmaxf(d * C0 + bH0.x, 0.f), q1 = fmaxf(d * C1 + bH0.y, 0.f);
    float q2 = fmaxf(d * C2 + bH0.z, 0.f), q3 = fmaxf(d * C3 + bH0.w, 0.f);
    float q4 = fmaxf(d * C4 + bH1.x, 0.f), q5 = fmaxf(d * C5 + bH1.y, 0.f);
    float q6 = fmaxf(d * C6 + bH1.z, 0.f), q7 = fmaxf(d * C7 + bH1.w, 0.f);
    if (MODE == 0) {
        uint4 wL, wH;
        wL.x = ((unsigned)(unsigned short)f2bf(p0)) | (((unsigned)(unsigned short)f2bf(p1)) << 16);
        wL.y = ((unsigned)(unsigned short)f2bf(p2)) | (((unsigned)(unsigned short)f2bf(p3)) << 16);
        wL.z = ((unsigned)(unsigned short)f2bf(p4)) | (((unsigned)(unsigned short)f2bf(p5)) << 16);
        wL.w = ((unsigned)(unsigned short)f2bf(p6)) | (((unsigned)(unsigned short)f2bf(p7)) << 16);
        wH.x = ((unsigned)(unsigned short)f2bf(q0)) | (((unsigned)(unsigned short)f2bf(q1)) << 16);
        wH.y = ((unsigned)(unsigned short)f2bf(q2)) | (((unsigned)(unsigned short)f2bf(q3)) << 16);
        wH.z = ((unsigned)(unsigned short)f2bf(q4)) | (((unsigned)(unsigned short)f2bf(q5)) << 16);
        wH.w = ((unsigned)(unsigned short)f2bf(q6)) | (((unsigned)(unsigned short)f2bf(q7)) << 16);
        ((uint4*)outp)[n * 16 + c4] = wL;       // hidden is reused by gemm2: keep cached
        ((uint4*)outp)[n * 16 + 8 + c4] = wH;
    } else {
        // half 0 == x1 exactly; half 1 == x2 exactly (64 ch each, fp32)
        // nontemporal: final output stream must not evict the 12.8 MB gather working set
        float* out0 = (float*)outp;
        float* out1 = (float*)outp + (size_t)N_NODES * 64;
        floatx4* o0 = (floatx4*)out0 + n * 16 + c4 * 2;
        floatx4* o1 = (floatx4*)out1 + n * 16 + c4 * 2;
        floatx4 w0; w0.x = p0; w0.y = p1; w0.z = p2; w0.w = p3;
        floatx4 w1; w1.x = p4; w1.y = p5; w1.z = p6; w1.w = p7;
        floatx4 w2; w2.x = q0; w2.y = q1; w2.z = q2; w2.w = q3;
        floatx4 w3; w3.x = q4; w3.y = q5; w3.z = q6; w3.w = q7;
        __builtin_nontemporal_store(w0, o0);
        __builtin_nontemporal_store(w1, o0 + 1);
        __builtin_nontemporal_store(w2, o1);
        __builtin_nontemporal_store(w3, o1 + 1);
    }
}

// ---------------- launch ----------------

extern "C" void kernel_launch(void* const* d_in, const int* in_sizes, int n_in,
                              void* d_out, int out_size, void* d_ws, size_t ws_size,
                              hipStream_t stream) {
    const float* x  = (const float*)d_in[0];
    const int*   ei = (const int*)d_in[1];   // [2, E] int32
    const float* W1 = (const float*)d_in[2];
    const float* b1 = (const float*)d_in[3];
    const float* W2 = (const float*)d_in[4];
    const float* b2 = (const float*)d_in[5];
    const float* W3 = (const float*)d_in[6];
    const float* b3 = (const float*)d_in[7];
    float* out = (float*)d_out;

    // Workspace layout (non-overlapping; total 37,083,392 B, previously proven)
    char* w = (char*)d_ws;
    int*            counts      = (int*)(w + 0);                   // 200,000 B (true degree)
    int*            bucket_cnt  = (int*)(w + 200704);              // 1,564 B
    unsigned short* Wt1         = (unsigned short*)(w + 204800);   // 32,768 B
    unsigned short* Wt23        = (unsigned short*)(w + 237568);   // 32,768 B
    float*          b23         = (float*)(w + 270336);            // 512 B
    unsigned*       bucket_data = (unsigned*)(w + 278528);         // 4,804,608 B
    unsigned short* sorted_src  = (unsigned short*)(w + 5083136);  // 6,400,000 B
    unsigned short* g1          = (unsigned short*)(w + 11483136); // 12,800,256 B (+dummy row)
    unsigned short* hidden      = (unsigned short*)(w + 24283392); // 12,800,000 B

    // prep (weights + bucket_cnt zero + zero dummy g row), then 2-phase CSR build
    prep_kernel<<<66, 256, 0, stream>>>(W1, W2, W3, b2, b3, Wt1, Wt23, b23, bucket_cnt,
                                        (unsigned int*)(g1 + N_NODES * 128));
    partition<<<PART_BLOCKS, 256, 0, stream>>>(ei, bucket_cnt, bucket_data);
    csr_build<<<NBUCK, 256, 0, stream>>>(bucket_data, bucket_cnt, counts, sorted_src);

    const int gemm_blocks = (N_NODES + 63) / 64;  // 782

    // layer 1: g1 = bf16(dinv * (x @ W1)); hidden = bf16(relu(dinv*(self+sum)+b1))
    gemm_mfma<false><<<gemm_blocks, 256, 0, stream>>>(x, Wt1, counts, g1);
    aggregate_bf16<0><<<AGG_BLKS, 256, 0, stream>>>(g1, counts, sorted_src, b1, hidden);

    // layers 2+3 fused: g1 = bf16(dinv * (hidden @ [W2|W3])); out = relu split
    gemm_mfma<true><<<gemm_blocks, 256, 0, stream>>>(hidden, Wt23, counts, g1);
    aggregate_bf16<1><<<AGG_BLKS, 256, 0, stream>>>(g1, counts, sorted_src, b23, out);
}